// Round 1
// baseline (5809.840 us; speedup 1.0000x reference)
//
#include <hip/hip_runtime.h>

// EQL network: 5-layer MLP + envelope argmax.
// Precision: f16 two-way split (hi/lo), 3 MFMAs per product (hh+hl+lh), 2^11
// pre-scale per operand so lo stays in f16 normal range -> ~2^-21 effective
// input precision, fp32 accumulate. Required because output 0 (hq) is an
// argmax-select over q.pref inner products.
// R4 -> R5: schedule restructure. Old loop was single-buffered
// stage -> syncthreads(vmcnt0 drain) -> compute per 32-K step: the m97-class
// 2-barrier drain structure (~33% MfmaUtil ceiling). New: 256x128xBK32 tile,
// 512 thr (8 waves, wave tile 64x64 = 2x2 frags of 32x32), TRIPLE-buffered
// LDS (3 x 48KB = 144KB), prefetch depth 2: during tile t issue the 6
// global_load_lds for tile t+2; tile boundary waits counted vmcnt(6) (never 0
// in steady state) + raw s_barrier; s_setprio(1) around MFMA clusters.
// Accumulation order per output element is unchanged -> bit-identical math.

#define AS1 __attribute__((address_space(1)))
#define AS3 __attribute__((address_space(3)))

typedef _Float16 half8 __attribute__((ext_vector_type(8)));
typedef float floatx16 __attribute__((ext_vector_type(16)));

static constexpr float SCALE = 2048.0f;                         // 2^11
static constexpr float INV_SCALE2 = 1.0f / (2048.0f * 2048.0f); // 2^-22

// -------------------------------------------------- weight split (strided src)
__global__ void split_w_kernel(const float* __restrict__ src, _Float16* __restrict__ hi,
                               _Float16* __restrict__ lo, int srcStride, int colOff,
                               int Kcopy, int Kpad) {
  int k = blockIdx.x * 256 + threadIdx.x;
  int n = blockIdx.y;
  if (k >= Kpad) return;
  float v = (k < Kcopy) ? src[(size_t)n * srcStride + colOff + k] * SCALE : 0.0f;
  _Float16 h = (_Float16)v;
  _Float16 l = (_Float16)(v - (float)h);
  size_t o = (size_t)n * Kpad + k;
  hi[o] = h;
  lo[o] = l;
}

// ------------------------------------------------------- x prep (concat+split)
__global__ void prep_x_kernel(const float* __restrict__ state, const float* __restrict__ pref,
                              _Float16* __restrict__ hi, _Float16* __restrict__ lo) {
  int k = threadIdx.x;
  int b = blockIdx.x;
  if (k >= 160) return;
  float v = 0.0f;
  if (k < 128) v = state[(size_t)b * 128 + k];
  else if (k < 132) v = pref[(size_t)b * 4 + (k - 128)];
  v *= SCALE;
  _Float16 h = (_Float16)v;
  _Float16 l = (_Float16)(v - (float)h);
  size_t o = (size_t)b * 160 + k;
  hi[o] = h;
  lo[o] = l;
}

// ------------------------------------------------------------ split-3 MFMA GEMM
// C[m][n] = sum_k A[m][k]*B[n][k]  (both K-contiguous). Tile 256x128xBK32,
// 512 thr = 8 waves (4 M x 2 N), wave = 64x64 via 2x2 frags of
// v_mfma_f32_32x32x16_f16. LDS: 3 buffers x 4 planes (Ahi 256x32, Alo 256x32,
// Bhi 128x32, Blo 128x32) f16, 48KB/buffer, staged global_load_lds width=16.
// Swizzle: logical (row r, granule g) lives at slot 4r+(g^((r>>1)&3)); slot%8
// (the 4-bank group) covers all 8 groups per 32 rows -> conflict-free reads;
// staging writes are 64 consecutive slots per (j,wave) -> linear.
// Pipeline: prologue stages tiles 0,1 into bufs 0,1. During tile t, issue the
// 6 loads for tile t+2 into buf (t+2)%3 (3 in each phase). Loop-top waits
// s_waitcnt vmcnt(6) (tile t+1's loads may stay in flight) + raw s_barrier.
// Phases per tile: kh=0 reads+12 MFMA, s_barrier, kh=1 reads+12 MFMA.
// K range per block: [blockIdx.z*kPerZ, +kPerZ).
// mode 0: Ohi/Olo = split( relu(acc*2^-22 + bias[col]) * 2^11 )
// mode 1: Oacc[(bz*Mrows+row)*N+col] = acc*2^-22 (+ old if accAdd)
// mode 2: v = acc*2^-22 + Oacc[row*N+col]; Ohi/Olo = split(relu(v+bias)*2^11)
__global__ __launch_bounds__(512) void gemm3_kernel(
    const _Float16* __restrict__ Ahi, const _Float16* __restrict__ Alo,
    const _Float16* __restrict__ Bhi, const _Float16* __restrict__ Blo,
    const float* __restrict__ bias,
    _Float16* __restrict__ Ohi, _Float16* __restrict__ Olo,
    float* __restrict__ Oacc,
    int K, int N, int kPerZ, int mode, int accAdd, int Mrows) {
  // per buffer (halfs): Ahi @0 (8192), Alo @8192, Bhi @16384 (4096), Blo @20480
  __shared__ __attribute__((aligned(16))) _Float16 lds[3 * 24576];  // 144 KB
  const int tid = threadIdx.x;
  const int wave = tid >> 6;
  const int lane = tid & 63;
  const int m0 = blockIdx.x * 256;
  const int n0 = blockIdx.y * 128;
  const int kBeg = blockIdx.z * kPerZ;

  // staging: 6 x 16B slots per thread per K-tile. Global slot q = j*512+tid:
  // q<1024 Ahi, <2048 Alo, <2560 Bhi, else Blo. Physical slot p within plane
  // holds logical (row r = p>>2, granule g = (p&3)^((r>>1)&3)).
  const _Float16* gp[6];
  int ldsoff[6];  // wave-uniform (depends on j, wave only)
#pragma unroll
  for (int j = 0; j < 6; ++j) {
    int q = j * 512 + tid;
    int plane, p;
    if (q < 1024)      { plane = 0; p = q; }
    else if (q < 2048) { plane = 1; p = q - 1024; }
    else if (q < 2560) { plane = 2; p = q - 2048; }
    else               { plane = 3; p = q - 2560; }
    const int r = p >> 2;
    const int g = (p & 3) ^ ((r >> 1) & 3);
    int row;
    const _Float16* ptr;
    if (plane < 2) {
      row = m0 + r;  // Mc is a multiple of 256
      ptr = plane ? Alo : Ahi;
    } else {
      row = n0 + r;
      if (row > N - 1) row = N - 1;  // tail N-tile: clamp (cols guarded at write)
      ptr = (plane == 3) ? Blo : Bhi;
    }
    gp[j] = ptr + (size_t)row * K + kBeg + 8 * g;
    int pbase = (plane == 0) ? 0 : (plane == 1) ? 8192 : (plane == 2) ? 16384 : 20480;
    ldsoff[j] = pbase + (p & ~63) * 8;
  }

  const int wm = wave >> 1, wn = wave & 1;
  floatx16 acc[2][2];
#pragma unroll
  for (int i = 0; i < 2; ++i)
#pragma unroll
    for (int j = 0; j < 2; ++j)
#pragma unroll
      for (int e = 0; e < 16; ++e) acc[i][j][e] = 0.0f;

  const int rA0 = (wm << 6) + (lane & 31);
  const int rB0 = (wn << 6) + (lane & 31);
  const int gHalf = lane >> 5;
  const int nT = kPerZ >> 5;

#define STAGEJ(J0, J1, BUF)                                                        \
  {                                                                                \
    const int bo_ = (BUF) * 24576;                                                 \
    _Pragma("unroll") for (int j = (J0); j <= (J1); ++j) {                         \
      __builtin_amdgcn_global_load_lds((const AS1 unsigned int*)gp[j],             \
                                       (AS3 unsigned int*)&lds[bo_ + ldsoff[j]],   \
                                       16, 0, 0);                                  \
      gp[j] += 32;                                                                 \
    }                                                                              \
  }

  // prologue: stage tiles 0 and 1
  STAGEJ(0, 5, 0)
  if (nT > 1) STAGEJ(0, 5, 1)

  int cb = 0, pb = 2;
  for (int t = 0; t < nT; ++t) {
    // boundary: tile t's 6 loads done; tile t+1's 6 may remain in flight
    if (t + 1 < nT) {
      asm volatile("s_waitcnt vmcnt(6)" ::: "memory");
    } else {
      asm volatile("s_waitcnt vmcnt(0)" ::: "memory");
    }
    __builtin_amdgcn_s_barrier();
    const int bo = cb * 24576;

    half8 ah[2], al[2], bh[2], bl[2];
    // ---- phase 0: k 0..15 of tile; prefetch first half of tile t+2
    if (t + 2 < nT) STAGEJ(0, 2, pb)
#pragma unroll
    for (int i = 0; i < 2; ++i) {
      int rA = rA0 + (i << 5);
      int sA = (rA << 2) + (gHalf ^ ((rA >> 1) & 3));
      ah[i] = *(const half8*)&lds[bo + sA * 8];
      al[i] = *(const half8*)&lds[bo + 8192 + sA * 8];
      int rB = rB0 + (i << 5);
      int sB = (rB << 2) + (gHalf ^ ((rB >> 1) & 3));
      bh[i] = *(const half8*)&lds[bo + 16384 + sB * 8];
      bl[i] = *(const half8*)&lds[bo + 20480 + sB * 8];
    }
    __builtin_amdgcn_s_setprio(1);
#pragma unroll
    for (int i = 0; i < 2; ++i)
#pragma unroll
      for (int j = 0; j < 2; ++j) {
        acc[i][j] = __builtin_amdgcn_mfma_f32_32x32x16_f16(ah[i], bh[j], acc[i][j], 0, 0, 0);
        acc[i][j] = __builtin_amdgcn_mfma_f32_32x32x16_f16(ah[i], bl[j], acc[i][j], 0, 0, 0);
        acc[i][j] = __builtin_amdgcn_mfma_f32_32x32x16_f16(al[i], bh[j], acc[i][j], 0, 0, 0);
      }
    __builtin_amdgcn_s_setprio(0);
    __builtin_amdgcn_s_barrier();

    // ---- phase 1: k 16..31 of tile; prefetch second half of tile t+2
    if (t + 2 < nT) STAGEJ(3, 5, pb)
#pragma unroll
    for (int i = 0; i < 2; ++i) {
      int rA = rA0 + (i << 5);
      int sA = (rA << 2) + ((2 + gHalf) ^ ((rA >> 1) & 3));
      ah[i] = *(const half8*)&lds[bo + sA * 8];
      al[i] = *(const half8*)&lds[bo + 8192 + sA * 8];
      int rB = rB0 + (i << 5);
      int sB = (rB << 2) + ((2 + gHalf) ^ ((rB >> 1) & 3));
      bh[i] = *(const half8*)&lds[bo + 16384 + sB * 8];
      bl[i] = *(const half8*)&lds[bo + 20480 + sB * 8];
    }
    __builtin_amdgcn_s_setprio(1);
#pragma unroll
    for (int i = 0; i < 2; ++i)
#pragma unroll
      for (int j = 0; j < 2; ++j) {
        acc[i][j] = __builtin_amdgcn_mfma_f32_32x32x16_f16(ah[i], bh[j], acc[i][j], 0, 0, 0);
        acc[i][j] = __builtin_amdgcn_mfma_f32_32x32x16_f16(ah[i], bl[j], acc[i][j], 0, 0, 0);
        acc[i][j] = __builtin_amdgcn_mfma_f32_32x32x16_f16(al[i], bh[j], acc[i][j], 0, 0, 0);
      }
    __builtin_amdgcn_s_setprio(0);

    cb = (cb == 2) ? 0 : cb + 1;
    pb = (pb == 2) ? 0 : pb + 1;
  }
#undef STAGEJ

  // C/D layout: col = lane&31, row = (e&3) + 8*(e>>2) + 4*(lane>>5)  [m74/m101]
#pragma unroll
  for (int i = 0; i < 2; ++i)
#pragma unroll
    for (int j = 0; j < 2; ++j)
#pragma unroll
      for (int e = 0; e < 16; ++e) {
        int row = m0 + (wm << 6) + (i << 5) + ((e & 3) + ((e >> 2) << 3) + ((lane >> 5) << 2));
        int col = n0 + (wn << 6) + (j << 5) + (lane & 31);
        if (col < N) {
          float v = acc[i][j][e] * INV_SCALE2;
          if (mode == 0) {
            size_t o = (size_t)row * N + col;
            v = fmaxf(v + bias[col], 0.0f) * SCALE;
            _Float16 h = (_Float16)v;
            _Float16 l = (_Float16)(v - (float)h);
            Ohi[o] = h;
            Olo[o] = l;
          } else if (mode == 1) {
            size_t o = ((size_t)blockIdx.z * Mrows + row) * N + col;
            if (accAdd) v += Oacc[o];
            Oacc[o] = v;
          } else {  // mode 2: finalize L4 -> split H4 planes
            size_t o = (size_t)row * N + col;
            v += Oacc[o];
            v = fmaxf(v + bias[col], 0.0f) * SCALE;
            _Float16 h = (_Float16)v;
            _Float16 l = (_Float16)(v - (float)h);
            Ohi[o] = h;
            Olo[o] = l;
          }
        }
      }
}

// --------------------------------- reduce split-K partials + envelope argmax
// One thread per row. QP layout [4][Mc][64] fp32.
__global__ __launch_bounds__(128) void finish_kernel(
    const float* __restrict__ part, const float* __restrict__ bq,
    const float* __restrict__ pref, float* __restrict__ out, int rowBase, int Mc) {
  int b = blockIdx.x * 128 + threadIdx.x;  // chunk-local row
  if (b >= Mc) return;
  float q[64];
#pragma unroll
  for (int o4 = 0; o4 < 16; ++o4) {
    float4 s = *(const float4*)&part[(size_t)b * 64 + o4 * 4];
    float4 s1 = *(const float4*)&part[(size_t)(Mc + b) * 64 + o4 * 4];
    float4 s2 = *(const float4*)&part[(size_t)(2 * Mc + b) * 64 + o4 * 4];
    float4 s3 = *(const float4*)&part[(size_t)(3 * Mc + b) * 64 + o4 * 4];
    float4 bb = *(const float4*)&bq[o4 * 4];
    q[o4 * 4 + 0] = s.x + s1.x + s2.x + s3.x + bb.x;
    q[o4 * 4 + 1] = s.y + s1.y + s2.y + s3.y + bb.y;
    q[o4 * 4 + 2] = s.z + s1.z + s2.z + s3.z + bb.z;
    q[o4 * 4 + 3] = s.w + s1.w + s2.w + s3.w + bb.w;
  }
  int g = rowBase + b;
  float* qout = out + 32768 + (size_t)g * 64;
#pragma unroll
  for (int o4 = 0; o4 < 16; ++o4)
    *(float4*)&qout[o4 * 4] = make_float4(q[o4 * 4], q[o4 * 4 + 1], q[o4 * 4 + 2], q[o4 * 4 + 3]);
  float p0 = pref[(size_t)g * 4 + 0], p1 = pref[(size_t)g * 4 + 1];
  float p2 = pref[(size_t)g * 4 + 2], p3 = pref[(size_t)g * 4 + 3];
  float best = q[0] * p0 + q[1] * p1 + q[2] * p2 + q[3] * p3;
  int ba = 0;
#pragma unroll
  for (int a = 1; a < 16; ++a) {
    float ip = q[4 * a] * p0 + q[4 * a + 1] * p1 + q[4 * a + 2] * p2 + q[4 * a + 3] * p3;
    if (ip > best) { best = ip; ba = a; }  // strict > == first-tie jnp.argmax
  }
  *(float4*)&out[(size_t)g * 4] =
      make_float4(q[4 * ba], q[4 * ba + 1], q[4 * ba + 2], q[4 * ba + 3]);
}

// ------------------------------------------------------------------- launcher
extern "C" void kernel_launch(void* const* d_in, const int* in_sizes, int n_in,
                              void* d_out, int out_size, void* d_ws, size_t ws_size,
                              hipStream_t stream) {
  const float* state = (const float*)d_in[0];
  const float* pref = (const float*)d_in[1];
  const float* w1 = (const float*)d_in[2];
  const float* b1 = (const float*)d_in[3];
  const float* w2 = (const float*)d_in[4];
  const float* b2 = (const float*)d_in[5];
  const float* w3 = (const float*)d_in[6];
  const float* b3 = (const float*)d_in[7];
  const float* w4 = (const float*)d_in[8];
  const float* b4 = (const float*)d_in[9];
  const float* wq = (const float*)d_in[10];
  const float* bq = (const float*)d_in[11];

  char* ws = (char*)d_ws;
  size_t off = 0;
  auto take = [&](size_t bytes) {
    size_t r = off;
    off += (bytes + 255) & ~(size_t)255;
    return r;
  };
  const size_t oW1h = take((size_t)2112 * 160 * 2);
  const size_t oW1l = take((size_t)2112 * 160 * 2);
  const size_t oW2h = take((size_t)4224 * 2112 * 2);
  const size_t oW2l = take((size_t)4224 * 2112 * 2);
  const size_t oW3h = take((size_t)2112 * 4224 * 2);  // quarter N-chunk of W3
  const size_t oW3l = take((size_t)2112 * 4224 * 2);
  const size_t oW4h = take((size_t)4224 * 2112 * 2);  // quarter K-slice of W4
  const size_t oW4l = take((size_t)4224 * 2112 * 2);
  const size_t oW5h = take((size_t)64 * 4224 * 2);
  const size_t oW5l = take((size_t)64 * 4224 * 2);
  const size_t fixed = off;

  // per-row bytes: X 640 + H1 8448 + H2 16896 + H3 8448 + ACC 16896 = 51328
  // (H4 overlays H2; QP overlays H1)
  int Mc = 8192;
  while (Mc > 256 && fixed + (size_t)Mc * 51328 + 4096 > ws_size) Mc >>= 1;

  const size_t oXh = take((size_t)Mc * 160 * 2);
  const size_t oXl = take((size_t)Mc * 160 * 2);
  const size_t oH1h = take((size_t)Mc * 2112 * 2);
  const size_t oH1l = take((size_t)Mc * 2112 * 2);
  const size_t oH2h = take((size_t)Mc * 4224 * 2);
  const size_t oH2l = take((size_t)Mc * 4224 * 2);
  const size_t oH3h = take((size_t)Mc * 2112 * 2);
  const size_t oH3l = take((size_t)Mc * 2112 * 2);
  const size_t oACC = take((size_t)Mc * 4224 * 4);

  _Float16* W1h = (_Float16*)(ws + oW1h);
  _Float16* W1l = (_Float16*)(ws + oW1l);
  _Float16* W2h = (_Float16*)(ws + oW2h);
  _Float16* W2l = (_Float16*)(ws + oW2l);
  _Float16* W3h = (_Float16*)(ws + oW3h);
  _Float16* W3l = (_Float16*)(ws + oW3l);
  _Float16* W4h = (_Float16*)(ws + oW4h);
  _Float16* W4l = (_Float16*)(ws + oW4l);
  _Float16* W5h = (_Float16*)(ws + oW5h);
  _Float16* W5l = (_Float16*)(ws + oW5l);
  _Float16* Xh = (_Float16*)(ws + oXh);
  _Float16* Xl = (_Float16*)(ws + oXl);
  _Float16* H1h = (_Float16*)(ws + oH1h);
  _Float16* H1l = (_Float16*)(ws + oH1l);
  _Float16* H2h = (_Float16*)(ws + oH2h);
  _Float16* H2l = (_Float16*)(ws + oH2l);
  _Float16* H3h = (_Float16*)(ws + oH3h);
  _Float16* H3l = (_Float16*)(ws + oH3l);
  float* ACC = (float*)(ws + oACC);
  _Float16* H4h = H2h;           // overlays H2 (dead after last L3)
  _Float16* H4l = H2l;
  float* QP = (float*)(ws + oH1h);  // overlays H1 (dead after L2)

  // persistent weight splits (W1 padded 132->160)
  split_w_kernel<<<dim3(1, 2112), 256, 0, stream>>>(w1, W1h, W1l, 132, 0, 132, 160);
  split_w_kernel<<<dim3(9, 4224), 256, 0, stream>>>(w2, W2h, W2l, 2112, 0, 2112, 2112);
  split_w_kernel<<<dim3(17, 64), 256, 0, stream>>>(wq, W5h, W5l, 4224, 0, 4224, 4224);

  const int NC = 8192 / Mc;
  const int GX = Mc / 256;  // BM=256
  for (int mc = 0; mc < NC; ++mc) {
    const float* st = state + (size_t)mc * Mc * 128;
    const float* pf = pref + (size_t)mc * Mc * 4;
    prep_x_kernel<<<dim3(Mc), 192, 0, stream>>>(st, pf, Xh, Xl);
    // L1: [Mc,160] x [2112,160]
    gemm3_kernel<<<dim3(GX, 17), 512, 0, stream>>>(Xh, Xl, W1h, W1l, b1, H1h, H1l,
                                                   nullptr, 160, 2112, 160, 0, 0, Mc);
    // L2: K=2112 -> N=4224
    gemm3_kernel<<<dim3(GX, 33), 512, 0, stream>>>(H1h, H1l, W2h, W2l, b2, H2h, H2l,
                                                   nullptr, 2112, 4224, 2112, 0, 0, Mc);
    // L3/L4 fused over 4 N-chunks of H3 (2112 each); ACC accumulates L4;
    // last chunk finalizes relu+b4 and writes split H4 planes (over H2).
    for (int c = 0; c < 4; ++c) {
      split_w_kernel<<<dim3(17, 2112), 256, 0, stream>>>(w3 + (size_t)c * 2112 * 4224, W3h,
                                                         W3l, 4224, 0, 4224, 4224);
      split_w_kernel<<<dim3(9, 4224), 256, 0, stream>>>(w4, W4h, W4l, 8448, c * 2112, 2112,
                                                        2112);
      gemm3_kernel<<<dim3(GX, 17), 512, 0, stream>>>(H2h, H2l, W3h, W3l, b3 + c * 2112,
                                                     H3h, H3l, nullptr, 4224, 2112, 4224,
                                                     0, 0, Mc);
      if (c < 3) {
        gemm3_kernel<<<dim3(GX, 33), 512, 0, stream>>>(H3h, H3l, W4h, W4l, nullptr, nullptr,
                                                       nullptr, ACC, 2112, 4224, 2112, 1,
                                                       c > 0 ? 1 : 0, Mc);
      } else {
        gemm3_kernel<<<dim3(GX, 33), 512, 0, stream>>>(H3h, H3l, W4h, W4l, b4, H4h, H4l,
                                                       ACC, 2112, 4224, 2112, 2, 0, Mc);
      }
    }
    // L5: [Mc,4224] x [64,4224], split-K=4 -> QP fp32 partials
    gemm3_kernel<<<dim3(GX, 1, 4), 512, 0, stream>>>(H4h, H4l, W5h, W5l, nullptr, nullptr,
                                                     nullptr, QP, 4224, 64, 1056, 1, 0, Mc);
    // reduce partials + bq, write q, envelope argmax -> hq
    finish_kernel<<<dim3(Mc / 128), 128, 0, stream>>>(QP, bq, pref, (float*)d_out,
                                                      mc * Mc, Mc);
  }
}